// Round 1
// baseline (2005.418 us; speedup 1.0000x reference)
//
#include <hip/hip_runtime.h>

#define TT 512
#define BB 512
#define II 8
#define HH 256
#define ST 296   // padded LDS row stride (halfs): 592B = 37*16B, breaks pow2 bank patterns

typedef _Float16 h4_t  __attribute__((ext_vector_type(4)));
typedef _Float16 h8_t  __attribute__((ext_vector_type(8)));
typedef float    f32x4 __attribute__((ext_vector_type(4)));

__device__ inline h8_t cvt8(const float* __restrict__ p, float s) {
    h8_t r;
#pragma unroll
    for (int i = 0; i < 8; ++i) r[i] = (_Float16)(p[i] * s);
    return r;
}

// Persistent GRU: 32 blocks x 1024 threads. Block owns 16 batch rows.
// Wave w owns gate columns [w*16, w*16+16) of each gate region (r,z,n).
// W_hh fragments live in registers (f16, pre-scaled for exp2-based gates).
// h state double-buffered in LDS as [row][k] f16 with x_t and bias-one
// appended at k=256..264 so gi+gh fuse into one MFMA chain.
__global__ void __launch_bounds__(1024) gru_kernel(
    const float* __restrict__ x,    const float* __restrict__ W_ih,
    const float* __restrict__ W_hh, const float* __restrict__ b_ih,
    const float* __restrict__ b_hh, const float* __restrict__ W_lin,
    const float* __restrict__ b_lin, float* __restrict__ out)
{
    __shared__ _Float16 hbuf[2][16][ST];
    __shared__ _Float16 wlin[HH];

    const int tid  = threadIdx.x;
    const int w    = tid >> 6;     // wave 0..15
    const int lane = tid & 63;
    const int q    = lane >> 4;    // quad 0..3
    const int r15  = lane & 15;
    const int row0 = blockIdx.x * 16;

    // scales fold log2(e) into the weights:
    //   sigmoid(a) = rcp(1 + exp2(-a*log2e));  tanh(y) = 1 - 2*rcp(1 + exp2(2y*log2e))
    const float sRZ = -1.44269504088896340736f;
    const float sN  =  2.88539008177792681472f;

    const int colR = w * 16 + r15;   // W row index for r-gate
    const int colZ = 256 + colR;     // z-gate
    const int colN = 512 + colR;     // n-gate

    // ---- W_hh -> register B-fragments (16x16x32_f16: lane holds B[n=lane&15][k=q*8+j]) ----
    h8_t wfR[8], wfZ[8], wfN[8];
#pragma unroll
    for (int s = 0; s < 8; ++s) {
        const int k0 = s * 32 + q * 8;
        wfR[s] = cvt8(W_hh + (size_t)colR * HH + k0, sRZ);
        wfZ[s] = cvt8(W_hh + (size_t)colZ * HH + k0, sRZ);
        wfN[s] = cvt8(W_hh + (size_t)colN * HH + k0, sN);
    }
    // ---- x-part B-fragments (16x16x16f16: lane holds B[n=lane&15][k'=q*4+j]) over [x(8)|bias(1)|0..] ----
    h4_t xfR, xfZ, xfN;
#pragma unroll
    for (int j = 0; j < 4; ++j) {
        const int kp = q * 4 + j;
        float vR = 0.f, vZ = 0.f, vN = 0.f;
        if (kp < 8) {
            vR = W_ih[colR * II + kp] * sRZ;
            vZ = W_ih[colZ * II + kp] * sRZ;
            vN = W_ih[colN * II + kp] * sN;
        } else if (kp == 8) {
            vR = (b_ih[colR] + b_hh[colR]) * sRZ;
            vZ = (b_ih[colZ] + b_hh[colZ]) * sRZ;
            vN = b_ih[colN] * sN;          // b_hh_n must ride inside r*(.), kept separate below
        }
        xfR[j] = (_Float16)vR; xfZ[j] = (_Float16)vZ; xfN[j] = (_Float16)vN;
    }
    const float bhn  = b_hh[colN] * sN;
    const float blin = b_lin[0];

    // ---- LDS init: zero both buffers, bias-one at k=264, x_0 into buf0 ----
    for (int i = tid; i < 2 * 16 * ST; i += 1024) (&hbuf[0][0][0])[i] = (_Float16)0.f;
    if (tid < HH) wlin[tid] = (_Float16)W_lin[tid];
    __syncthreads();
    if (tid < 32) hbuf[tid >> 4][tid & 15][264] = (_Float16)1.f;
    if (tid < 128) {
        const int rr_ = tid >> 3, ii = tid & 7;
        hbuf[0][rr_][256 + ii] = (_Float16)x[((size_t)(row0 + rr_) * TT + 0) * II + ii];
    }
    __syncthreads();

    f32x4 hreg = {0.f, 0.f, 0.f, 0.f};     // this wave's h at (row=q*4+j, col=w*16+r15)
    const f32x4 z4 = {0.f, 0.f, 0.f, 0.f};

    for (int t = 0; t < TT; ++t) {
        const int cur = t & 1, nxt = cur ^ 1;

        // prefetch x_{t+1} (lanes 0..7 carry row w's 8 inputs)
        float xv = 0.f;
        {
            const int tn = (t + 1 < TT) ? t + 1 : TT - 1;
            if (lane < II) xv = x[((size_t)(row0 + w) * TT + tn) * II + lane];
        }

        // A-fragments from LDS (A[m=lane&15][k=q*8+j]); fused gi+gh MFMA chains
        const _Float16* hb = &hbuf[cur][r15][0];
        const h4_t a2 = *(const h4_t*)(hb + 256 + q * 4);
        f32x4 accR = __builtin_amdgcn_mfma_f32_16x16x16f16(a2, xfR, z4, 0, 0, 0);
        f32x4 accZ = __builtin_amdgcn_mfma_f32_16x16x16f16(a2, xfZ, z4, 0, 0, 0);
        f32x4 gin  = __builtin_amdgcn_mfma_f32_16x16x16f16(a2, xfN, z4, 0, 0, 0);
        f32x4 accN = z4;
#pragma unroll
        for (int s = 0; s < 8; ++s) {
            const h8_t a = *(const h8_t*)(hb + s * 32 + q * 8);
            accR = __builtin_amdgcn_mfma_f32_16x16x32_f16(a, wfR[s], accR, 0, 0, 0);
            accZ = __builtin_amdgcn_mfma_f32_16x16x32_f16(a, wfZ[s], accZ, 0, 0, 0);
            accN = __builtin_amdgcn_mfma_f32_16x16x32_f16(a, wfN[s], accN, 0, 0, 0);
        }

        // gates (C/D layout: col=lane&15, row=q*4+j). 3 exp2 + 3 rcp per position.
#pragma unroll
        for (int j = 0; j < 4; ++j) {
            const float rr = __builtin_amdgcn_rcpf(1.f + __builtin_amdgcn_exp2f(accR[j]));
            const float zz = __builtin_amdgcn_rcpf(1.f + __builtin_amdgcn_exp2f(accZ[j]));
            const float u  = gin[j] + rr * (accN[j] + bhn);
            const float nn = 1.f - 2.f * __builtin_amdgcn_rcpf(1.f + __builtin_amdgcn_exp2f(u));
            const float hv = nn + zz * (hreg[j] - nn);
            hreg[j] = hv;
            hbuf[nxt][q * 4 + j][w * 16 + r15] = (_Float16)hv;
        }
        if (lane < II) hbuf[nxt][w][256 + lane] = (_Float16)xv;

        __syncthreads();   // single barrier per step: publishes h_t (+x_{t+1}) in buf nxt

        // pred_t = h_t . W_lin + b_lin  (wave w reduces row w from LDS)
        {
            const h4_t hv4 = *(const h4_t*)&hbuf[nxt][w][lane * 4];
            const h4_t wl4 = *(const h4_t*)&wlin[lane * 4];
            float s0 = (float)hv4[0] * (float)wl4[0] + (float)hv4[1] * (float)wl4[1]
                     + (float)hv4[2] * (float)wl4[2] + (float)hv4[3] * (float)wl4[3];
#pragma unroll
            for (int m = 32; m >= 1; m >>= 1) s0 += __shfl_xor(s0, m, 64);
            if (lane == 0) out[(size_t)(row0 + w) * TT + t] = s0 + blin;
        }
    }
}

extern "C" void kernel_launch(void* const* d_in, const int* in_sizes, int n_in,
                              void* d_out, int out_size, void* d_ws, size_t ws_size,
                              hipStream_t stream) {
    const float* x     = (const float*)d_in[0];
    const float* W_ih  = (const float*)d_in[1];
    const float* W_hh  = (const float*)d_in[2];
    const float* b_ih  = (const float*)d_in[3];
    const float* b_hh  = (const float*)d_in[4];
    const float* W_lin = (const float*)d_in[5];
    const float* b_lin = (const float*)d_in[6];
    float* out = (float*)d_out;
    gru_kernel<<<32, 1024, 0, stream>>>(x, W_ih, W_hh, b_ih, b_hh, W_lin, b_lin, out);
}

// Round 3
// 2001.144 us; speedup vs baseline: 1.0021x; 1.0021x over previous
//
#include <hip/hip_runtime.h>

#define TT 512
#define BB 512
#define II 8
#define HH 256
#define ST 296   // padded LDS row stride (halfs): 592B = 37*16B, breaks pow2 bank patterns

typedef _Float16 h4_t  __attribute__((ext_vector_type(4)));
typedef _Float16 h8_t  __attribute__((ext_vector_type(8)));
typedef float    f32x4 __attribute__((ext_vector_type(4)));

__device__ inline h8_t cvt8(const float* __restrict__ p, float s) {
    h8_t r;
#pragma unroll
    for (int i = 0; i < 8; ++i) r[i] = (_Float16)(p[i] * s);
    return r;
}

// Persistent GRU: 32 blocks x 1024 threads (16 waves = 4 waves/SIMD).
// Block owns 16 batch rows. Wave w owns gate columns [w*16, w*16+16) of r,z,n.
// W_hh lives in registers as f16 MFMA B-fragments (48 VGPRs/lane).
// __launch_bounds__(1024, 4) raises the VGPR cap to 128: at the default
// 64-VGPR target the W fragments spill to scratch and the kernel runs 5x
// slower (measured R1: 2005us, WRITE_SIZE 15.6MB of spill stores).
// This source is otherwise IDENTICAL to the R1 kernel that passed
// correctness (absmax 1.95e-3): x-frags stay in registers.
__global__ void __launch_bounds__(1024, 4) gru_kernel(
    const float* __restrict__ x,    const float* __restrict__ W_ih,
    const float* __restrict__ W_hh, const float* __restrict__ b_ih,
    const float* __restrict__ b_hh, const float* __restrict__ W_lin,
    const float* __restrict__ b_lin, float* __restrict__ out)
{
    __shared__ _Float16 hbuf[2][16][ST];
    __shared__ _Float16 wlin[HH];

    const int tid  = threadIdx.x;
    const int w    = tid >> 6;     // wave 0..15
    const int lane = tid & 63;
    const int q    = lane >> 4;    // quad 0..3
    const int r15  = lane & 15;
    const int row0 = blockIdx.x * 16;

    // scales fold log2(e) into the weights:
    //   sigmoid(a) = rcp(1 + exp2(-a*log2e));  tanh(y) = 1 - 2*rcp(1 + exp2(2y*log2e))
    const float sRZ = -1.44269504088896340736f;
    const float sN  =  2.88539008177792681472f;

    const int colR = w * 16 + r15;   // W row index for r-gate
    const int colZ = 256 + colR;     // z-gate
    const int colN = 512 + colR;     // n-gate

    // ---- W_hh -> register B-fragments (16x16x32_f16: lane holds B[n=lane&15][k=q*8+j]) ----
    h8_t wfR[8], wfZ[8], wfN[8];
#pragma unroll
    for (int s = 0; s < 8; ++s) {
        const int k0 = s * 32 + q * 8;
        wfR[s] = cvt8(W_hh + (size_t)colR * HH + k0, sRZ);
        wfZ[s] = cvt8(W_hh + (size_t)colZ * HH + k0, sRZ);
        wfN[s] = cvt8(W_hh + (size_t)colN * HH + k0, sN);
    }
    // ---- x-part B-fragments (16x16x16f16: lane holds B[n=lane&15][k'=q*4+j]) over [x(8)|bias(1)|0..] ----
    h4_t xfR, xfZ, xfN;
#pragma unroll
    for (int j = 0; j < 4; ++j) {
        const int kp = q * 4 + j;
        float vR = 0.f, vZ = 0.f, vN = 0.f;
        if (kp < 8) {
            vR = W_ih[colR * II + kp] * sRZ;
            vZ = W_ih[colZ * II + kp] * sRZ;
            vN = W_ih[colN * II + kp] * sN;
        } else if (kp == 8) {
            vR = (b_ih[colR] + b_hh[colR]) * sRZ;
            vZ = (b_ih[colZ] + b_hh[colZ]) * sRZ;
            vN = b_ih[colN] * sN;          // b_hh_n must ride inside r*(.), kept separate below
        }
        xfR[j] = (_Float16)vR; xfZ[j] = (_Float16)vZ; xfN[j] = (_Float16)vN;
    }
    const float bhn  = b_hh[colN] * sN;
    const float blin = b_lin[0];

    // ---- LDS init: zero both buffers, bias-one at k=264, x_0 into buf0 ----
    for (int i = tid; i < 2 * 16 * ST; i += 1024) (&hbuf[0][0][0])[i] = (_Float16)0.f;
    if (tid < HH) wlin[tid] = (_Float16)W_lin[tid];
    __syncthreads();
    if (tid < 32) hbuf[tid >> 4][tid & 15][264] = (_Float16)1.f;
    if (tid < 128) {
        const int rr_ = tid >> 3, ii = tid & 7;
        hbuf[0][rr_][256 + ii] = (_Float16)x[((size_t)(row0 + rr_) * TT + 0) * II + ii];
    }
    __syncthreads();

    f32x4 hreg = {0.f, 0.f, 0.f, 0.f};     // this wave's h at (row=q*4+j, col=w*16+r15)
    const f32x4 z4 = {0.f, 0.f, 0.f, 0.f};

    for (int t = 0; t < TT; ++t) {
        const int cur = t & 1, nxt = cur ^ 1;

        // prefetch x_{t+1} (lanes 0..7 carry row w's 8 inputs)
        float xv = 0.f;
        {
            const int tn = (t + 1 < TT) ? t + 1 : TT - 1;
            if (lane < II) xv = x[((size_t)(row0 + w) * TT + tn) * II + lane];
        }

        // A-fragments from LDS (A[m=lane&15][k=q*8+j]); fused gi+gh MFMA chains
        const _Float16* hb = &hbuf[cur][r15][0];
        const h4_t a2 = *(const h4_t*)(hb + 256 + q * 4);
        f32x4 accR = __builtin_amdgcn_mfma_f32_16x16x16f16(a2, xfR, z4, 0, 0, 0);
        f32x4 accZ = __builtin_amdgcn_mfma_f32_16x16x16f16(a2, xfZ, z4, 0, 0, 0);
        f32x4 gin  = __builtin_amdgcn_mfma_f32_16x16x16f16(a2, xfN, z4, 0, 0, 0);
        f32x4 accN = z4;
#pragma unroll
        for (int s = 0; s < 8; ++s) {
            const h8_t a = *(const h8_t*)(hb + s * 32 + q * 8);
            accR = __builtin_amdgcn_mfma_f32_16x16x32_f16(a, wfR[s], accR, 0, 0, 0);
            accZ = __builtin_amdgcn_mfma_f32_16x16x32_f16(a, wfZ[s], accZ, 0, 0, 0);
            accN = __builtin_amdgcn_mfma_f32_16x16x32_f16(a, wfN[s], accN, 0, 0, 0);
        }

        // gates (C/D layout: col=lane&15, row=q*4+j). 3 exp2 + 3 rcp per position.
#pragma unroll
        for (int j = 0; j < 4; ++j) {
            const float rr = __builtin_amdgcn_rcpf(1.f + __builtin_amdgcn_exp2f(accR[j]));
            const float zz = __builtin_amdgcn_rcpf(1.f + __builtin_amdgcn_exp2f(accZ[j]));
            const float u  = gin[j] + rr * (accN[j] + bhn);
            const float nn = 1.f - 2.f * __builtin_amdgcn_rcpf(1.f + __builtin_amdgcn_exp2f(u));
            const float hv = nn + zz * (hreg[j] - nn);
            hreg[j] = hv;
            hbuf[nxt][q * 4 + j][w * 16 + r15] = (_Float16)hv;
        }
        if (lane < II) hbuf[nxt][w][256 + lane] = (_Float16)xv;

        __syncthreads();   // single barrier per step: publishes h_t (+x_{t+1}) in buf nxt

        // pred_t = h_t . W_lin + b_lin  (wave w reduces row w from LDS)
        {
            const h4_t hv4 = *(const h4_t*)&hbuf[nxt][w][lane * 4];
            const h4_t wl4 = *(const h4_t*)&wlin[lane * 4];
            float s0 = (float)hv4[0] * (float)wl4[0] + (float)hv4[1] * (float)wl4[1]
                     + (float)hv4[2] * (float)wl4[2] + (float)hv4[3] * (float)wl4[3];
#pragma unroll
            for (int m = 32; m >= 1; m >>= 1) s0 += __shfl_xor(s0, m, 64);
            if (lane == 0) out[(size_t)(row0 + w) * TT + t] = s0 + blin;
        }
    }
}

extern "C" void kernel_launch(void* const* d_in, const int* in_sizes, int n_in,
                              void* d_out, int out_size, void* d_ws, size_t ws_size,
                              hipStream_t stream) {
    const float* x     = (const float*)d_in[0];
    const float* W_ih  = (const float*)d_in[1];
    const float* W_hh  = (const float*)d_in[2];
    const float* b_ih  = (const float*)d_in[3];
    const float* b_hh  = (const float*)d_in[4];
    const float* W_lin = (const float*)d_in[5];
    const float* b_lin = (const float*)d_in[6];
    float* out = (float*)d_out;
    gru_kernel<<<32, 1024, 0, stream>>>(x, W_ih, W_hh, b_ih, b_hh, W_lin, b_lin, out);
}